// Round 5
// baseline (109.297 us; speedup 1.0000x reference)
//
#include <hip/hip_runtime.h>
#include <math.h>

#define BB 256      // batch
#define CC 1024     // channels
#define CC4 (CC/4)  // row length in float4
#define MARGIN 0.5f
#define NTILE 64    // j-tiles (of 4) per row
#define JPT 4       // j's per tile
#define NP  128     // i-pairs

// ---------------------------------------------------------------------------
// Wave reduction with the SAME summation tree as the old xor-butterfly
// (off = 32,16,8,4,2,1) but with steps 8/4/2/1 on the VALU pipe via DPP:
//   row_ror:8  == xor8 exactly (within 16-lane rows);
//   row_ror:4  == xor4 for lanes 0-3 (mod 16) — lane-0 tree exact;
//   quad_perm(2,3,0,1) == xor2, quad_perm(1,0,3,2) == xor1 (exact).
// Old butterfly left ALL lanes with the identical lane-0-tree value, so
// broadcasting lane 0 via readfirstlane reproduces it bit-exactly.
// Only 2 LDS-pipe ops (shfl 32/16) instead of 6.
// ---------------------------------------------------------------------------
template<int CTRL>
__device__ __forceinline__ float dpp_add(float v) {
    const int pi = __builtin_amdgcn_update_dpp(
        0, __float_as_int(v), CTRL, 0xF, 0xF, false);
    return v + __int_as_float(pi);
}
__device__ __forceinline__ float wred(float v) {
    v += __shfl_xor(v, 32, 64);
    v += __shfl_xor(v, 16, 64);
    v = dpp_add<0x128>(v);   // row_ror:8  == xor8
    v = dpp_add<0x124>(v);   // row_ror:4  (lane-0 tree exact)
    v = dpp_add<0x4E>(v);    // quad_perm 2,3,0,1 == xor2
    v = dpp_add<0xB1>(v);    // quad_perm 1,0,3,2 == xor1
    return __int_as_float(__builtin_amdgcn_readfirstlane(__float_as_int(v)));
}

// ---------------------------------------------------------------------------
// Kernel A: mcsq[i,c] = m_counts[i,c]^2 (float). Unchanged.
// ---------------------------------------------------------------------------
__global__ __launch_bounds__(64) void mcsq_kernel(
    const float* __restrict__ x, const int* __restrict__ targets,
    const int* __restrict__ subs, const int* __restrict__ m_count_p,
    float* __restrict__ mcsq, float* __restrict__ acc,
    unsigned int* __restrict__ cnt_g)
{
    const int i = blockIdx.x;
    const int lane = threadIdx.x;
    if (i == 0 && lane == 0) { *acc = 0.f; *cnt_g = 0u; }
    const int ti = targets[i], si = subs[i];
    int mc = *m_count_p;
    if (mc > 8) mc = 8;

    unsigned long long masks[4];
    #pragma unroll
    for (int q = 0; q < 4; ++q) {
        const int j = q * 64 + lane;
        masks[q] = __ballot(targets[j] == ti && subs[j] == si);
    }
    int idx[8];
    int cnt = 0;
    for (int q = 0; q < 4 && cnt < mc; ++q) {
        unsigned long long m = masks[q];
        while (m && cnt < mc) {
            const int b = __ffsll(m) - 1;
            idx[cnt++] = q * 64 + b;
            m &= m - 1;
        }
    }
    for (int q = 0; q < 4 && cnt < mc; ++q) {   // stable-argsort padding
        unsigned long long m = ~masks[q];
        while (m && cnt < mc) {
            const int b = __ffsll(m) - 1;
            idx[cnt++] = q * 64 + b;
            m &= m - 1;
        }
    }

    const float4* x4 = (const float4*)x;
    float4 xi[4];
    #pragma unroll
    for (int t = 0; t < 4; ++t) xi[t] = x4[(long)i * CC4 + lane + 64 * t];

    float4 c4[4];
    #pragma unroll
    for (int t = 0; t < 4; ++t) c4[t] = make_float4(0.f, 0.f, 0.f, 0.f);

    for (int k = 0; k < cnt; ++k) {
        float4 ad[4];
        float s = 0.f;
        #pragma unroll
        for (int t = 0; t < 4; ++t) {
            const float4 xj = x4[(long)idx[k] * CC4 + lane + 64 * t];
            ad[t].x = fabsf(xi[t].x - xj.x);
            ad[t].y = fabsf(xi[t].y - xj.y);
            ad[t].z = fabsf(xi[t].z - xj.z);
            ad[t].w = fabsf(xi[t].w - xj.w);
            s += ad[t].x + ad[t].y + ad[t].z + ad[t].w;
        }
        #pragma unroll
        for (int off = 32; off > 0; off >>= 1) s += __shfl_xor(s, off, 64);
        const float thr = s * (MARGIN / CC);   // 0.5 * mean
        #pragma unroll
        for (int t = 0; t < 4; ++t) {
            c4[t].x += (ad[t].x < thr) ? 1.f : 0.f;
            c4[t].y += (ad[t].y < thr) ? 1.f : 0.f;
            c4[t].z += (ad[t].z < thr) ? 1.f : 0.f;
            c4[t].w += (ad[t].w < thr) ? 1.f : 0.f;
        }
    }
    float4* m4 = (float4*)mcsq;
    #pragma unroll
    for (int t = 0; t < 4; ++t) {
        float4 o;
        o.x = c4[t].x * c4[t].x;
        o.y = c4[t].y * c4[t].y;
        o.z = c4[t].z * c4[t].z;
        o.w = c4[t].w * c4[t].w;
        m4[(long)i * CC4 + lane + 64 * t] = o;
    }
}

// ---------------------------------------------------------------------------
// Kernel B: TRIANGULAR pair kernel. Wave = 2 i-rows (pair p) x 2 jt-chunks
// (4 j's each), j-rows read from GLOBAL (L2-resident; LDS pipe freed for
// nothing — reductions are DPP/VALU now, no staging, no barriers).
// 2112 uniform waves = 528 blocks x 4 waves, all co-resident in ONE
// generation (launch_bounds(256,4) -> 4 blocks/CU capacity = 1024 >= 528).
// Wave W -> (h, p, jt0): per h (=p>>1), waves-per-p ch = ceil((64-h)/2);
// chunk rc covers jt = h+2rc, h+2rc+1 (guarded <= 63).
// Per-(i,j) arithmetic sequence identical to R1 -> bit-exact (absmax 0).
// Outputs: pmax/pmin[i][jt] (i-side), pmaxT/pminT[j][p] (j-side, NP=128).
// ---------------------------------------------------------------------------
__global__ __launch_bounds__(256, 4) void pair_kernel(
    const float* __restrict__ x, const float* __restrict__ mcsq,
    const int* __restrict__ targets,
    float* __restrict__ pmax, float* __restrict__ pmin,
    float* __restrict__ pmaxT, float* __restrict__ pminT)
{
    const int tid  = threadIdx.x;
    const int lane = tid & 63;
    const int W    = blockIdx.x * 4 + (tid >> 6);   // 0..2111

    // decode W -> h, p, jt0 (wave-uniform scalar loop, <=64 iters)
    int h = 0, C = 0;
    while (true) {
        const int c2 = 2 * ((65 - h) >> 1);         // 2*ceil((64-h)/2)
        if (C + c2 > W) break;
        C += c2; ++h;
    }
    const int ch  = (65 - h) >> 1;                  // waves per p at this h
    const int r   = W - C;                          // 0..2ch-1
    const int p   = 2 * h + ((r >= ch) ? 1 : 0);
    const int rc  = (r >= ch) ? (r - ch) : r;
    const int jt0 = h + 2 * rc;

    const int i0 = 2 * p, i1 = 2 * p + 1;

    const float4* x4 = (const float4*)x;
    const float4* m4 = (const float4*)mcsq;

    float4 xi0[4], xi1[4], mi0[4], mi1[4];
    #pragma unroll
    for (int t = 0; t < 4; ++t) {
        const int c4 = lane + 64 * t;
        xi0[t] = x4[(long)i0 * CC4 + c4];
        xi1[t] = x4[(long)i1 * CC4 + c4];
        mi0[t] = m4[(long)i0 * CC4 + c4];
        mi1[t] = m4[(long)i1 * CC4 + c4];
    }
    const int t0 = targets[i0], t1 = targets[i1];

    #pragma unroll
    for (int q = 0; q < 2; ++q) {
        const int jt = jt0 + q;
        if (jt > 63) break;

        float max0 = 0.f, max1 = 0.f;
        float min0 = INFINITY, min1 = INFINITY;

        #pragma unroll
        for (int jj = 0; jj < JPT; ++jj) {
            const int j = jt * JPT + jj;

            float4 xa[4], ma[4];
            float s0 = 0.f, s1 = 0.f;
            #pragma unroll
            for (int t = 0; t < 4; ++t) {
                const int c4 = lane + 64 * t;
                xa[t] = x4[(long)j * CC4 + c4];
                s0 += fabsf(xi0[t].x - xa[t].x) + fabsf(xi0[t].y - xa[t].y)
                    + fabsf(xi0[t].z - xa[t].z) + fabsf(xi0[t].w - xa[t].w);
                s1 += fabsf(xi1[t].x - xa[t].x) + fabsf(xi1[t].y - xa[t].y)
                    + fabsf(xi1[t].z - xa[t].z) + fabsf(xi1[t].w - xa[t].w);
            }
            #pragma unroll
            for (int t = 0; t < 4; ++t)
                ma[t] = m4[(long)j * CC4 + lane + 64 * t];

            const float thr0 = wred(s0) * (MARGIN / CC);
            const float thr1 = wred(s1) * (MARGIN / CC);

            float ids0 = 0.f, ids1 = 0.f, md0 = 0.f, md1 = 0.f;
            #pragma unroll
            for (int t = 0; t < 4; ++t) {
                #pragma unroll
                for (int u = 0; u < 4; ++u) {
                    const float xav = (&xa[t].x)[u];
                    const float mav = (&ma[t].x)[u];
                    const float d0 = (&xi0[t].x)[u] - xav;
                    const float q0 = d0 * d0;
                    ids0 += (fabsf(d0) < thr0) ? q0 : 0.f;
                    md0  += q0 * (&mi0[t].x)[u] * mav;
                    const float d1 = (&xi1[t].x)[u] - xav;
                    const float q1 = d1 * d1;
                    ids1 += (fabsf(d1) < thr1) ? q1 : 0.f;
                    md1  += q1 * (&mi1[t].x)[u] * mav;
                }
            }
            const float rds0 = wred(ids0);
            const float rds1 = wred(ids1);
            const float rmd0 = wred(md0);
            const float rmd1 = wred(md1);

            const float mod0 = sqrtf(fmaxf(rmd0, 1e-12f));
            const float mod1 = sqrtf(fmaxf(rmd1, 1e-12f));
            max0 = fmaxf(max0, mod0);
            max1 = fmaxf(max1, mod1);
            float id0 = sqrtf(fmaxf(rds0, 1e-12f));
            float id1 = sqrtf(fmaxf(rds1, 1e-12f));
            const int tj = targets[j];
            if (tj != t0) min0 = fminf(min0, id0); else id0 = INFINITY;
            if (tj != t1) min1 = fminf(min1, id1); else id1 = INFINITY;
            if (lane == 0) {                   // j-side (transposed) partials
                pmaxT[j * NP + p] = fmaxf(mod0, mod1);
                pminT[j * NP + p] = fminf(id0, id1);
            }
        }
        if (lane == 0) {                       // i-side partials
            pmax[i0 * NTILE + jt] = max0;
            pmax[i1 * NTILE + jt] = max1;
            pmin[i0 * NTILE + jt] = min0;
            pmin[i1 * NTILE + jt] = min1;
        }
    }
}

// ---------------------------------------------------------------------------
// Kernel C: parallel final reduce (R1 form). One wave per row: <=3 guarded
// loads per lane, 6-step max/min butterfly, atomicAdd of per_row/BB; last
// block publishes the total to d_out. Valid slots: i-side jt in [i/4, 64),
// transposed p < 2*(i/4)+2 — poisoned slots never read.
// ---------------------------------------------------------------------------
__global__ __launch_bounds__(64) void final_kernel(
    const float* __restrict__ pmax, const float* __restrict__ pmin,
    const float* __restrict__ pmaxT, const float* __restrict__ pminT,
    float* __restrict__ acc, unsigned int* __restrict__ cnt_g,
    float* __restrict__ out)
{
    const int i = blockIdx.x;       // row
    const int lane = threadIdx.x;
    const int s = i >> 2;
    float mx = 0.f, mn = INFINITY;
    const int t = s + lane;
    if (t < NTILE) {
        mx = fmaxf(mx, pmax[i * NTILE + t]);
        mn = fminf(mn, pmin[i * NTILE + t]);
    }
    const int pv = 2 * s + 2;
    if (lane < pv) {
        mx = fmaxf(mx, pmaxT[i * NP + lane]);
        mn = fminf(mn, pminT[i * NP + lane]);
    }
    if (lane + 64 < pv) {
        mx = fmaxf(mx, pmaxT[i * NP + lane + 64]);
        mn = fminf(mn, pminT[i * NP + lane + 64]);
    }
    #pragma unroll
    for (int off = 32; off > 0; off >>= 1) {
        mx = fmaxf(mx, __shfl_xor(mx, off, 64));
        mn = fminf(mn, __shfl_xor(mn, off, 64));
    }
    if (lane == 0) {
        const float per = fmaxf(mx * 10.f - mn, 0.f);
        atomicAdd(acc, per * (1.0f / BB));
        __threadfence();
        const unsigned int old = atomicAdd(cnt_g, 1u);
        if (old == BB - 1) {
            __threadfence();
            out[0] = atomicAdd(acc, 0.0f);   // device-coherent read-back
        }
    }
}

extern "C" void kernel_launch(void* const* d_in, const int* in_sizes, int n_in,
                              void* d_out, int out_size, void* d_ws, size_t ws_size,
                              hipStream_t stream)
{
    const float* x       = (const float*)d_in[0];
    const int*   targets = (const int*)d_in[1];
    const int*   subs    = (const int*)d_in[2];
    const int*   m_count = (const int*)d_in[3];
    float* out  = (float*)d_out;

    float* mcsq  = (float*)d_ws;                  // BB*CC floats = 1 MB
    float* pmax  = mcsq  + (long)BB * CC;         // BB*NTILE
    float* pmin  = pmax  + BB * NTILE;            // BB*NTILE
    float* pmaxT = pmin  + BB * NTILE;            // BB*NP
    float* pminT = pmaxT + BB * NP;               // BB*NP
    float* acc   = pminT + BB * NP;               // 1
    unsigned int* cnt_g = (unsigned int*)(acc + 1);

    mcsq_kernel <<<BB,  64, 0, stream>>>(x, targets, subs, m_count, mcsq, acc, cnt_g);
    pair_kernel <<<528, 256, 0, stream>>>(x, mcsq, targets, pmax, pmin, pmaxT, pminT);
    final_kernel<<<BB,  64, 0, stream>>>(pmax, pmin, pmaxT, pminT, acc, cnt_g, out);
}

// Round 6
// 95.142 us; speedup vs baseline: 1.1488x; 1.1488x over previous
//
#include <hip/hip_runtime.h>
#include <math.h>

#define BB 256      // batch
#define CC 1024     // channels
#define CC4 (CC/4)  // row length in float4
#define MARGIN 0.5f
#define NTILE 64    // j-tiles (of 4) per row
#define JPT 4       // j's per tile

// ---------------------------------------------------------------------------
// Wave reduction with the SAME summation tree as the xor-butterfly
// (off = 32,16,8,4,2,1): steps 32/16 via shfl_xor (LDS pipe), steps 8/4/2/1
// on the VALU pipe via DPP. All lanes of the old butterfly ended with the
// bit-identical value (same pairings per level, addition commutative), and
// wred broadcasts exactly that value. HW-verified bit-exact in R5 (absmax 0).
// ---------------------------------------------------------------------------
template<int CTRL>
__device__ __forceinline__ float dpp_add(float v) {
    const int pi = __builtin_amdgcn_update_dpp(
        0, __float_as_int(v), CTRL, 0xF, 0xF, false);
    return v + __int_as_float(pi);
}
__device__ __forceinline__ float wred(float v) {
    v += __shfl_xor(v, 32, 64);
    v += __shfl_xor(v, 16, 64);
    v = dpp_add<0x128>(v);   // row_ror:8  == xor8
    v = dpp_add<0x124>(v);   // row_ror:4  (lane-0 tree exact)
    v = dpp_add<0x4E>(v);    // quad_perm 2,3,0,1 == xor2
    v = dpp_add<0xB1>(v);    // quad_perm 1,0,3,2 == xor1
    return __int_as_float(__builtin_amdgcn_readfirstlane(__float_as_int(v)));
}

// ---------------------------------------------------------------------------
// Kernel A: mcsq[i,c] = m_counts[i,c]^2 (float). Unchanged.
// ---------------------------------------------------------------------------
__global__ __launch_bounds__(64) void mcsq_kernel(
    const float* __restrict__ x, const int* __restrict__ targets,
    const int* __restrict__ subs, const int* __restrict__ m_count_p,
    float* __restrict__ mcsq, float* __restrict__ acc,
    unsigned int* __restrict__ cnt_g)
{
    const int i = blockIdx.x;
    const int lane = threadIdx.x;
    if (i == 0 && lane == 0) { *acc = 0.f; *cnt_g = 0u; }
    const int ti = targets[i], si = subs[i];
    int mc = *m_count_p;
    if (mc > 8) mc = 8;

    unsigned long long masks[4];
    #pragma unroll
    for (int q = 0; q < 4; ++q) {
        const int j = q * 64 + lane;
        masks[q] = __ballot(targets[j] == ti && subs[j] == si);
    }
    int idx[8];
    int cnt = 0;
    for (int q = 0; q < 4 && cnt < mc; ++q) {
        unsigned long long m = masks[q];
        while (m && cnt < mc) {
            const int b = __ffsll(m) - 1;
            idx[cnt++] = q * 64 + b;
            m &= m - 1;
        }
    }
    for (int q = 0; q < 4 && cnt < mc; ++q) {   // stable-argsort padding
        unsigned long long m = ~masks[q];
        while (m && cnt < mc) {
            const int b = __ffsll(m) - 1;
            idx[cnt++] = q * 64 + b;
            m &= m - 1;
        }
    }

    const float4* x4 = (const float4*)x;
    float4 xi[4];
    #pragma unroll
    for (int t = 0; t < 4; ++t) xi[t] = x4[(long)i * CC4 + lane + 64 * t];

    float4 c4[4];
    #pragma unroll
    for (int t = 0; t < 4; ++t) c4[t] = make_float4(0.f, 0.f, 0.f, 0.f);

    for (int k = 0; k < cnt; ++k) {
        float4 ad[4];
        float s = 0.f;
        #pragma unroll
        for (int t = 0; t < 4; ++t) {
            const float4 xj = x4[(long)idx[k] * CC4 + lane + 64 * t];
            ad[t].x = fabsf(xi[t].x - xj.x);
            ad[t].y = fabsf(xi[t].y - xj.y);
            ad[t].z = fabsf(xi[t].z - xj.z);
            ad[t].w = fabsf(xi[t].w - xj.w);
            s += ad[t].x + ad[t].y + ad[t].z + ad[t].w;
        }
        #pragma unroll
        for (int off = 32; off > 0; off >>= 1) s += __shfl_xor(s, off, 64);
        const float thr = s * (MARGIN / CC);   // 0.5 * mean
        #pragma unroll
        for (int t = 0; t < 4; ++t) {
            c4[t].x += (ad[t].x < thr) ? 1.f : 0.f;
            c4[t].y += (ad[t].y < thr) ? 1.f : 0.f;
            c4[t].z += (ad[t].z < thr) ? 1.f : 0.f;
            c4[t].w += (ad[t].w < thr) ? 1.f : 0.f;
        }
    }
    float4* m4 = (float4*)mcsq;
    #pragma unroll
    for (int t = 0; t < 4; ++t) {
        float4 o;
        o.x = c4[t].x * c4[t].x;
        o.y = c4[t].y * c4[t].y;
        o.z = c4[t].z * c4[t].z;
        o.w = c4[t].w * c4[t].w;
        m4[(long)i * CC4 + lane + 64 * t] = o;
    }
}

// ---------------------------------------------------------------------------
// Kernel B: TRIANGULAR pair kernel, R4 frame + PHASE-SPLIT reductions.
// Block = (ig, jt), ig <= jt (2080 uniform blocks); 4 waves, i = ig*4 + w;
// 4 j-rows (x + mcsq) LDS-staged once per block.
// Per wave: PHASE 1 computes s for ALL 4 j's (xa transient), then ONE
// reduce pass with 4 concurrent tree chains; PHASE 2 runs the 4 masked
// passes (xa reloaded from LDS, ma loaded once), then ONE reduce pass with
// 8 concurrent chains. Tree traversals per wave drop 12 -> 2 passes;
// per-value tree shape and all per-(i,j) arithmetic order are IDENTICAL
// to R4 -> bit-exact (absmax must stay 0). No launch_bounds occupancy
// clause (R5's VGPR=64 spill trap).
// ---------------------------------------------------------------------------
__global__ __launch_bounds__(256) void pair_kernel(
    const float* __restrict__ x, const float* __restrict__ mcsq,
    const int* __restrict__ targets,
    float* __restrict__ pmax, float* __restrict__ pmin,
    float* __restrict__ pmaxT, float* __restrict__ pminT)
{
    const int tid  = threadIdx.x;
    const int lane = tid & 63;
    const int w    = tid >> 6;     // wave in block -> i within group
    const int b    = blockIdx.x;   // 0..2079

    // decode b -> (jt, ig): b = jt(jt+1)/2 + ig, ig in [0, jt]
    int jt = (int)((sqrtf(8.0f * (float)b + 1.0f) - 1.0f) * 0.5f);
    if (jt < 0) jt = 0;
    if (jt > 63) jt = 63;
    while (jt > 0 && (jt * (jt + 1)) / 2 > b) --jt;
    while (((jt + 1) * (jt + 2)) / 2 <= b) ++jt;
    const int ig = b - (jt * (jt + 1)) / 2;   // 0..jt
    const int i  = ig * 4 + w;                // wave's i-row
    const int j0 = jt * JPT;

    __shared__ float lds[8192];               // [0..4095]=x rows, [4096..]=mcsq rows
    float4* lds4 = (float4*)lds;

    const float4* x4 = (const float4*)x;
    const float4* m4 = (const float4*)mcsq;

    // --- hoist scalars ------------------------------------------------------
    const int ti = targets[i];
    int tj[4];
    #pragma unroll
    for (int q = 0; q < 4; ++q) tj[q] = targets[j0 + q];

    // --- i-row loads (per wave, registers) ---------------------------------
    float4 xi[4], mi[4];
    #pragma unroll
    for (int t = 0; t < 4; ++t) {
        const int c4 = lane + 64 * t;
        xi[t] = x4[(long)i * CC4 + c4];
        mi[t] = m4[(long)i * CC4 + c4];
    }

    // --- stage 4 j-rows of x and mcsq into LDS (256 thr x 8 float4) --------
    {
        float4 st[8];
        #pragma unroll
        for (int q = 0; q < 4; ++q) {
            st[q]     = x4[(long)(j0 + q) * CC4 + tid];
            st[4 + q] = m4[(long)(j0 + q) * CC4 + tid];
        }
        #pragma unroll
        for (int q = 0; q < 8; ++q) lds4[q * 256 + tid] = st[q];
    }
    __syncthreads();

    const float4* lx = lds4;                  // x rows: row*256 + c4
    const float4* lm = lds4 + 1024;           // mcsq rows

    // ======== PHASE 1: L1 sums for all 4 j's (xa transient) ================
    float sv[JPT];
    #pragma unroll
    for (int jj = 0; jj < JPT; ++jj) {
        float s = 0.f;
        #pragma unroll
        for (int t = 0; t < 4; ++t) {
            const float4 xa = lx[jj * 256 + lane + 64 * t];
            s += fabsf(xi[t].x - xa.x) + fabsf(xi[t].y - xa.y)
               + fabsf(xi[t].z - xa.z) + fabsf(xi[t].w - xa.w);
        }
        sv[jj] = s;
    }
    // one reduce pass, 4 concurrent chains
    float thr[JPT];
    #pragma unroll
    for (int jj = 0; jj < JPT; ++jj) thr[jj] = wred(sv[jj]) * (MARGIN / CC);

    // ======== PHASE 2: masked passes for all 4 j's =========================
    float ids[JPT], md[JPT];
    #pragma unroll
    for (int jj = 0; jj < JPT; ++jj) {
        float idv = 0.f, mdv = 0.f;
        const float th = thr[jj];
        #pragma unroll
        for (int t = 0; t < 4; ++t) {
            const float4 xa = lx[jj * 256 + lane + 64 * t];
            const float4 ma = lm[jj * 256 + lane + 64 * t];
            #pragma unroll
            for (int u = 0; u < 4; ++u) {
                const float xiv = (&xi[t].x)[u];
                const float miv = (&mi[t].x)[u];
                const float xav = (&xa.x)[u];
                const float mav = (&ma.x)[u];
                const float d = xiv - xav;
                const float q = d * d;
                idv += (fabsf(d) < th) ? q : 0.f;
                mdv += q * miv * mav;
            }
        }
        ids[jj] = idv;
        md[jj]  = mdv;
    }
    // one reduce pass, 8 concurrent chains
    #pragma unroll
    for (int jj = 0; jj < JPT; ++jj) {
        ids[jj] = wred(ids[jj]);
        md[jj]  = wred(md[jj]);
    }

    // ======== epilogue (same per-j order as R4) ============================
    float mx = 0.f, mn = INFINITY;
    #pragma unroll
    for (int jj = 0; jj < JPT; ++jj) {
        const int j = j0 + jj;
        const float mod = sqrtf(fmaxf(md[jj], 1e-12f));
        float idv = sqrtf(fmaxf(ids[jj], 1e-12f));
        mx = fmaxf(mx, mod);
        if (tj[jj] != ti) mn = fminf(mn, idv); else idv = INFINITY;
        if (lane == 0) {                      // j-side (transposed) partial
            pmaxT[j * BB + i] = mod;
            pminT[j * BB + i] = idv;
        }
    }
    if (lane == 0) {                          // i-side partials
        pmax[i * NTILE + jt] = mx;
        pmin[i * NTILE + jt] = mn;
    }
}

// ---------------------------------------------------------------------------
// Kernel C: parallel final reduce (R4 form). One wave per row: i-side jt in
// [i>>2, 64) (1 guarded load), transposed i' < 4*(i>>2)+4 (4 guarded loads);
// 6-step max/min butterfly; atomicAdd of per_row/BB; last block publishes to
// d_out. Poisoned (never-written) slots are never read.
// ---------------------------------------------------------------------------
__global__ __launch_bounds__(64) void final_kernel(
    const float* __restrict__ pmax, const float* __restrict__ pmin,
    const float* __restrict__ pmaxT, const float* __restrict__ pminT,
    float* __restrict__ acc, unsigned int* __restrict__ cnt_g,
    float* __restrict__ out)
{
    const int i = blockIdx.x;       // row
    const int lane = threadIdx.x;
    const int s = i >> 2;
    float mx = 0.f, mn = INFINITY;
    const int t = s + lane;
    if (t < NTILE) {
        mx = fmaxf(mx, pmax[i * NTILE + t]);
        mn = fminf(mn, pmin[i * NTILE + t]);
    }
    const int pv = 4 * s + 4;       // transposed valid i' count
    #pragma unroll
    for (int q = 0; q < 4; ++q) {
        const int c = lane + 64 * q;
        if (c < pv) {
            mx = fmaxf(mx, pmaxT[i * BB + c]);
            mn = fminf(mn, pminT[i * BB + c]);
        }
    }
    #pragma unroll
    for (int off = 32; off > 0; off >>= 1) {
        mx = fmaxf(mx, __shfl_xor(mx, off, 64));
        mn = fminf(mn, __shfl_xor(mn, off, 64));
    }
    if (lane == 0) {
        const float per = fmaxf(mx * 10.f - mn, 0.f);
        atomicAdd(acc, per * (1.0f / BB));
        __threadfence();
        const unsigned int old = atomicAdd(cnt_g, 1u);
        if (old == BB - 1) {
            __threadfence();
            out[0] = atomicAdd(acc, 0.0f);   // device-coherent read-back
        }
    }
}

extern "C" void kernel_launch(void* const* d_in, const int* in_sizes, int n_in,
                              void* d_out, int out_size, void* d_ws, size_t ws_size,
                              hipStream_t stream)
{
    const float* x       = (const float*)d_in[0];
    const int*   targets = (const int*)d_in[1];
    const int*   subs    = (const int*)d_in[2];
    const int*   m_count = (const int*)d_in[3];
    float* out  = (float*)d_out;

    float* mcsq  = (float*)d_ws;                  // BB*CC floats = 1 MB
    float* pmax  = mcsq  + (long)BB * CC;         // BB*NTILE
    float* pmin  = pmax  + BB * NTILE;            // BB*NTILE
    float* pmaxT = pmin  + BB * NTILE;            // BB*BB
    float* pminT = pmaxT + BB * BB;               // BB*BB
    float* acc   = pminT + BB * BB;               // 1
    unsigned int* cnt_g = (unsigned int*)(acc + 1);

    mcsq_kernel <<<BB,   64, 0, stream>>>(x, targets, subs, m_count, mcsq, acc, cnt_g);
    pair_kernel <<<2080, 256, 0, stream>>>(x, mcsq, targets, pmax, pmin, pmaxT, pminT);
    final_kernel<<<BB,   64, 0, stream>>>(pmax, pmin, pmaxT, pminT, acc, cnt_g, out);
}